// Round 1
// baseline (907.924 us; speedup 1.0000x reference)
//
#include <hip/hip_runtime.h>

#define NPT   4096
#define KNN_K 16
#define EPSV  1e-5f

// ---- ws float layout ----
// [0,4288)      w0t  [67][64]  (ic' major; ic'<64 -> points col ic'+3, ic'>=64 -> xyz col ic'-64)
// [4288,4352)   b0f  [64]
// [4352,8448)   w1t  [64][64]
// [8448,8512)   b1f  [64]
// [8512,16704)  w2g  [32][64][4]   (g-major groups of 4 output channels)
// [16704,16832) b2f  [128]
// [16832, ...)  knn idx  (int) [B*N*16]
#define W0T_OFF 0
#define B0_OFF  4288
#define W1T_OFF 4352
#define B1_OFF  8448
#define W2G_OFF 8512
#define B2_OFF  16704
#define IDX_OFF 16832

__global__ void prep_kernel(
    const float* __restrict__ w0, const float* __restrict__ b0, const float* __restrict__ g0,
    const float* __restrict__ be0, const float* __restrict__ rm0, const float* __restrict__ rv0,
    const float* __restrict__ w1, const float* __restrict__ b1, const float* __restrict__ g1,
    const float* __restrict__ be1, const float* __restrict__ rm1, const float* __restrict__ rv1,
    const float* __restrict__ w2, const float* __restrict__ b2, const float* __restrict__ g2,
    const float* __restrict__ be2, const float* __restrict__ rm2, const float* __restrict__ rv2,
    float* __restrict__ ws) {
  int i = blockIdx.x * 256 + threadIdx.x;
  if (i < 4288) {                        // w0t: [ic'][oc]
    int oc = i & 63, icp = i >> 6;
    int col = (icp < 64) ? (icp + 3) : (icp - 64);
    float s = g0[oc] * rsqrtf(rv0[oc] + EPSV);
    ws[W0T_OFF + i] = w0[oc * 67 + col] * s;
  } else if (i < 4352) {
    int oc = i - 4288;
    float s = g0[oc] * rsqrtf(rv0[oc] + EPSV);
    ws[i] = (b0[oc] - rm0[oc]) * s + be0[oc];
  } else if (i < 8448) {
    int j = i - 4352; int oc = j & 63, ic = j >> 6;
    float s = g1[oc] * rsqrtf(rv1[oc] + EPSV);
    ws[i] = w1[oc * 64 + ic] * s;
  } else if (i < 8512) {
    int oc = i - 8448;
    float s = g1[oc] * rsqrtf(rv1[oc] + EPSV);
    ws[i] = (b1[oc] - rm1[oc]) * s + be1[oc];
  } else if (i < 16704) {
    int j = i - 8512; int jj = j & 3, ic = (j >> 2) & 63, g = j >> 8;
    int oc = g * 4 + jj;
    float s = g2[oc] * rsqrtf(rv2[oc] + EPSV);
    ws[i] = w2[oc * 64 + ic] * s;
  } else if (i < 16832) {
    int oc = i - 16704;
    float s = g2[oc] * rsqrtf(rv2[oc] + EPSV);
    ws[i] = (b2[oc] - rm2[oc]) * s + be2[oc];
  }
}

// KNN: 128-thread blocks, 2 waves; each wave: 16 queries x 4 candidate-slices.
// Slice s scans m = 4t+s (t=0..1023) -> the 4 distinct LDS float4 reads per
// iteration are consecutive -> bank-conflict-free broadcast to 16 lanes each.
// Selection key: monotone-uint(d2) << 32 | m  -> strict < == lax.top_k order.
__global__ __launch_bounds__(128) void knn_kernel(
    const float* __restrict__ xyz, int* __restrict__ knnOut) {
  __shared__ __align__(16) float4 cand[NPT];                 // 64 KB
  unsigned long long* L = (unsigned long long*)cand;         // reused after scan
  int tid = threadIdx.x;
  int lane = tid & 63, wave = tid >> 6;
  int b = blockIdx.x >> 7;                                   // 128 blocks/batch
  int qb = ((blockIdx.x & 127) << 5) + (wave << 4);          // 16 queries/wave
  const float* xb = xyz + b * NPT * 3;

  for (int i = tid; i < NPT; i += 128) {
    float x = xb[i * 3], y = xb[i * 3 + 1], z = xb[i * 3 + 2];
    float sq = __fadd_rn(__fadd_rn(__fmul_rn(x, x), __fmul_rn(y, y)), __fmul_rn(z, z));
    cand[i] = make_float4(x, y, z, sq);
  }
  __syncthreads();

  int s = lane >> 4;
  int qi = lane & 15;
  int n = qb + qi;
  float4 q = cand[n];

  unsigned long long h[16];
#pragma unroll
  for (int j = 0; j < 16; ++j) h[j] = 0xFFFFFFFFFFFFFFFFull;

  for (int t = 0; t < 1024; ++t) {
    int m = (t << 2) | s;
    float4 c = cand[m];
    float dot = __fadd_rn(__fadd_rn(__fmul_rn(q.x, c.x), __fmul_rn(q.y, c.y)),
                          __fmul_rn(q.z, c.z));
    float d2 = __fsub_rn(__fadd_rn(q.w, c.w), __fmul_rn(2.0f, dot));
    unsigned int bits = __float_as_uint(d2);
    unsigned int fk = bits ^ (0x80000000u | (unsigned int)((int)bits >> 31));
    unsigned long long key = ((unsigned long long)fk << 32) | (unsigned int)m;
    if (key < h[15]) {
      h[15] = key;
#pragma unroll
      for (int j = 15; j > 0; --j) {
        unsigned long long a = h[j - 1], c2 = h[j];
        bool sw = c2 < a;
        h[j] = sw ? a : c2;
        h[j - 1] = sw ? c2 : a;
      }
    }
  }
  __syncthreads();   // both waves done scanning before lists clobber cand
#pragma unroll
  for (int j = 0; j < 16; ++j) L[(wave * 64 + lane) * 16 + j] = h[j];
  __syncthreads();

  if (lane < 16) {   // 4-way merge of sorted 16-lists, smallest-16 set
    const unsigned long long* l0 = L + (wave * 64 + 0  + lane) * 16;
    const unsigned long long* l1 = L + (wave * 64 + 16 + lane) * 16;
    const unsigned long long* l2 = L + (wave * 64 + 32 + lane) * 16;
    const unsigned long long* l3 = L + (wave * 64 + 48 + lane) * 16;
    int p0 = 0, p1 = 0, p2 = 0, p3 = 0;
    unsigned long long h0 = l0[0], h1v = l1[0], h2 = l2[0], h3 = l3[0];
    int* dst = knnOut + (b * NPT + qb + lane) * KNN_K;
    for (int r = 0; r < KNN_K; ++r) {
      unsigned long long best = h0; int which = 0;
      if (h1v < best) { best = h1v; which = 1; }
      if (h2  < best) { best = h2;  which = 2; }
      if (h3  < best) { best = h3;  which = 3; }
      dst[r] = (int)(unsigned int)best;
      if (which == 0)      { ++p0; h0  = (p0 < 16) ? l0[p0] : 0xFFFFFFFFFFFFFFFFull; }
      else if (which == 1) { ++p1; h1v = (p1 < 16) ? l1[p1] : 0xFFFFFFFFFFFFFFFFull; }
      else if (which == 2) { ++p2; h2  = (p2 < 16) ? l2[p2] : 0xFFFFFFFFFFFFFFFFull; }
      else                 { ++p3; h3  = (p3 < 16) ? l3[p3] : 0xFFFFFFFFFFFFFFFFull; }
    }
  }
}

// MLP: 128-thread blocks = 8 queries x 16 neighbors. Thread-private LDS row
// (stride 68 floats, 16B-aligned) holds features then relu(h0); h1 lives in
// registers into layer 2. Weights via block-uniform index -> s_load.
__global__ __launch_bounds__(128) void mlp_kernel(
    const float* __restrict__ xyz, const float* __restrict__ points,
    const float* __restrict__ wbuf, const int* __restrict__ knn,
    float* __restrict__ out) {
  __shared__ __align__(16) float feat[128 * 68];  // 34816 B
  int tid = threadIdx.x;
  int k = tid & 15, qi = tid >> 4;
  int b = blockIdx.x >> 9;                        // 512 blocks/batch
  int n = ((blockIdx.x & 511) << 3) + qi;
  int center = b * NPT + n;
  int nIdx = knn[center * KNN_K + k];
  int src = b * NPT + nIdx;

  float* row = feat + tid * 68;
  const float4* prow = (const float4*)(points + (size_t)src * 64);
#pragma unroll
  for (int j = 0; j < 16; ++j) ((float4*)row)[j] = prow[j];
  row[64] = xyz[src * 3 + 0] - xyz[center * 3 + 0];
  row[65] = xyz[src * 3 + 1] - xyz[center * 3 + 1];
  row[66] = xyz[src * 3 + 2] - xyz[center * 3 + 2];

  const float* w0t = wbuf + W0T_OFF;
  const float* b0f = wbuf + B0_OFF;
  const float* w1t = wbuf + W1T_OFF;
  const float* b1f = wbuf + B1_OFF;
  const float* w2g = wbuf + W2G_OFF;
  const float* b2f = wbuf + B2_OFF;

  float acc[64];
#pragma unroll
  for (int oc = 0; oc < 64; ++oc) acc[oc] = b0f[oc];
#pragma unroll 1
  for (int ic = 0; ic < 67; ++ic) {
    float x = row[ic];
    const float* w = w0t + ic * 64;
#pragma unroll
    for (int oc = 0; oc < 64; ++oc) acc[oc] = fmaf(w[oc], x, acc[oc]);
  }
#pragma unroll
  for (int oc = 0; oc < 64; ++oc) row[oc] = fmaxf(acc[oc], 0.0f);

#pragma unroll
  for (int oc = 0; oc < 64; ++oc) acc[oc] = b1f[oc];
#pragma unroll 1
  for (int ic = 0; ic < 64; ++ic) {
    float x = row[ic];
    const float* w = w1t + ic * 64;
#pragma unroll
    for (int oc = 0; oc < 64; ++oc) acc[oc] = fmaf(w[oc], x, acc[oc]);
  }
  float h1[64];
#pragma unroll
  for (int oc = 0; oc < 64; ++oc) h1[oc] = fmaxf(acc[oc], 0.0f);

  float4* outRow = (float4*)(out + (size_t)center * 128);
#pragma unroll 1
  for (int g = 0; g < 32; ++g) {
    const float* w = w2g + g * 256;
    float a0 = b2f[g * 4 + 0], a1 = b2f[g * 4 + 1];
    float a2 = b2f[g * 4 + 2], a3 = b2f[g * 4 + 3];
#pragma unroll
    for (int ic = 0; ic < 64; ++ic) {
      float x = h1[ic];
      a0 = fmaf(w[ic * 4 + 0], x, a0);
      a1 = fmaf(w[ic * 4 + 1], x, a1);
      a2 = fmaf(w[ic * 4 + 2], x, a2);
      a3 = fmaf(w[ic * 4 + 3], x, a3);
    }
    a0 = fmaxf(a0, 0.0f); a1 = fmaxf(a1, 0.0f);
    a2 = fmaxf(a2, 0.0f); a3 = fmaxf(a3, 0.0f);
#pragma unroll
    for (int off = 8; off; off >>= 1) {
      a0 = fmaxf(a0, __shfl_xor(a0, off));
      a1 = fmaxf(a1, __shfl_xor(a1, off));
      a2 = fmaxf(a2, __shfl_xor(a2, off));
      a3 = fmaxf(a3, __shfl_xor(a3, off));
    }
    if (k == 0) outRow[g] = make_float4(a0, a1, a2, a3);
  }
}

extern "C" void kernel_launch(void* const* d_in, const int* in_sizes, int n_in,
                              void* d_out, int out_size, void* d_ws, size_t ws_size,
                              hipStream_t stream) {
  const float* xyz    = (const float*)d_in[0];
  const float* points = (const float*)d_in[1];
  float* wsF = (float*)d_ws;
  int* idxBuf = (int*)(wsF + IDX_OFF);

  prep_kernel<<<66, 256, 0, stream>>>(
      (const float*)d_in[2],  (const float*)d_in[3],  (const float*)d_in[4],
      (const float*)d_in[5],  (const float*)d_in[6],  (const float*)d_in[7],
      (const float*)d_in[8],  (const float*)d_in[9],  (const float*)d_in[10],
      (const float*)d_in[11], (const float*)d_in[12], (const float*)d_in[13],
      (const float*)d_in[14], (const float*)d_in[15], (const float*)d_in[16],
      (const float*)d_in[17], (const float*)d_in[18], (const float*)d_in[19],
      wsF);
  knn_kernel<<<512, 128, 0, stream>>>(xyz, idxBuf);
  mlp_kernel<<<2048, 128, 0, stream>>>(xyz, points, wsF, idxBuf, (float*)d_out);
}

// Round 2
// 442.444 us; speedup vs baseline: 2.0521x; 2.0521x over previous
//
#include <hip/hip_runtime.h>

#define NPT   4096
#define KNN_K 16
#define EPSV  1e-5f

// ---- ws float layout ----
#define W0T_OFF 0
#define B0_OFF  4288
#define W1T_OFF 4352
#define B1_OFF  8448
#define W2G_OFF 8512
#define B2_OFF  16704
#define IDX_OFF 16832              // int[4*4096*16] = 262144 ints
#define XYZ4_OFF 278976            // float4[4*4096] (byte offset divisible by 16)

typedef unsigned long long ull;

__global__ void prep_kernel(
    const float* __restrict__ xyz,
    const float* __restrict__ w0, const float* __restrict__ b0, const float* __restrict__ g0,
    const float* __restrict__ be0, const float* __restrict__ rm0, const float* __restrict__ rv0,
    const float* __restrict__ w1, const float* __restrict__ b1, const float* __restrict__ g1,
    const float* __restrict__ be1, const float* __restrict__ rm1, const float* __restrict__ rv1,
    const float* __restrict__ w2, const float* __restrict__ b2, const float* __restrict__ g2,
    const float* __restrict__ be2, const float* __restrict__ rm2, const float* __restrict__ rv2,
    float* __restrict__ ws) {
  int blk = blockIdx.x;
  if (blk < 64) {                        // xyz -> (x,y,z,sq) float4, exact ref arithmetic
    int i = blk * 256 + threadIdx.x;     // [0, 16384)
    const float* p = xyz + i * 3;
    float x = p[0], y = p[1], z = p[2];
    float sq = __fadd_rn(__fadd_rn(__fmul_rn(x, x), __fmul_rn(y, y)), __fmul_rn(z, z));
    ((float4*)(ws + XYZ4_OFF))[i] = make_float4(x, y, z, sq);
    return;
  }
  int i = (blk - 64) * 256 + threadIdx.x;
  if (i < 4288) {                        // w0t: [ic'][oc]
    int oc = i & 63, icp = i >> 6;
    int col = (icp < 64) ? (icp + 3) : (icp - 64);
    float s = g0[oc] * rsqrtf(rv0[oc] + EPSV);
    ws[W0T_OFF + i] = w0[oc * 67 + col] * s;
  } else if (i < 4352) {
    int oc = i - 4288;
    float s = g0[oc] * rsqrtf(rv0[oc] + EPSV);
    ws[i] = (b0[oc] - rm0[oc]) * s + be0[oc];
  } else if (i < 8448) {
    int j = i - 4352; int oc = j & 63, ic = j >> 6;
    float s = g1[oc] * rsqrtf(rv1[oc] + EPSV);
    ws[i] = w1[oc * 64 + ic] * s;
  } else if (i < 8512) {
    int oc = i - 8448;
    float s = g1[oc] * rsqrtf(rv1[oc] + EPSV);
    ws[i] = (b1[oc] - rm1[oc]) * s + be1[oc];
  } else if (i < 16704) {
    int j = i - 8512; int jj = j & 3, ic = (j >> 2) & 63, g = j >> 8;
    int oc = g * 4 + jj;
    float s = g2[oc] * rsqrtf(rv2[oc] + EPSV);
    ws[i] = w2[oc * 64 + ic] * s;
  } else if (i < 16832) {
    int oc = i - 16704;
    float s = g2[oc] * rsqrtf(rv2[oc] + EPSV);
    ws[i] = (b2[oc] - rm2[oc]) * s + be2[oc];
  }
}

__device__ __forceinline__ ull minu64(ull a, ull b) { return a < b ? a : b; }
__device__ __forceinline__ ull maxu64(ull a, ull b) { return a > b ? a : b; }

// full ascending bitonic sort of 64 keys (1/lane) across a wave
__device__ __forceinline__ ull bitonic_sort64(ull v, int lane) {
#pragma unroll
  for (int k = 2; k <= 64; k <<= 1) {
#pragma unroll
    for (int j = k >> 1; j > 0; j >>= 1) {
      ull o = __shfl_xor(v, j);
      bool lower = (lane & j) == 0;
      bool up = (lane & k) == 0;
      v = (lower == up) ? minu64(v, o) : maxu64(v, o);
    }
  }
  return v;
}

// ascending sort of a bitonic sequence
__device__ __forceinline__ ull bitonic_merge64(ull v, int lane) {
#pragma unroll
  for (int j = 32; j > 0; j >>= 1) {
    ull o = __shfl_xor(v, j);
    v = ((lane & j) == 0) ? minu64(v, o) : maxu64(v, o);
  }
  return v;
}

// KNN: one wave per query. Threshold-filter (running 16th-smallest key) +
// LDS compaction buffer + wave-wide bitonic sort/merge flushes.
// Key = monotone-uint(d2) << 32 | idx  -> strict < reproduces lax.top_k set.
__global__ __launch_bounds__(256) void knn_kernel(const float4* __restrict__ cand4,
                                                  int* __restrict__ knnOut) {
  __shared__ __align__(16) float4 tile[1024];   // 16 KB candidate tile (shared by 4 waves)
  __shared__ ull buf[4][128];                   // per-wave compaction buffer, 4 KB
  int tid = threadIdx.x;
  int lane = tid & 63, w = tid >> 6;
  int b = blockIdx.x >> 10;                     // 1024 blocks/batch, 4 queries/block
  int n = ((blockIdx.x & 1023) << 2) + w;
  const float4* cb = cand4 + b * NPT;

  float4 q = cb[n];                             // wave-uniform -> broadcast load
  ull R = ~0ull;                                // sorted asc result (64-wide)
  ull thresh = ~0ull;                           // R[15] = running 16th smallest
  int cnt = 0;
  ull ltmask = (lane == 0) ? 0ull : (~0ull >> (64 - lane));

#pragma unroll 1
  for (int t = 0; t < 4; ++t) {
    __syncthreads();
#pragma unroll
    for (int j = 0; j < 4; ++j) tile[j * 256 + tid] = cb[t * 1024 + j * 256 + tid];
    __syncthreads();
#pragma unroll 1
    for (int i = 0; i < 16; ++i) {
      int ml = (i << 6) + lane;
      float4 c = tile[ml];
      float dot = __fadd_rn(__fadd_rn(__fmul_rn(q.x, c.x), __fmul_rn(q.y, c.y)),
                            __fmul_rn(q.z, c.z));
      float d2 = __fsub_rn(__fadd_rn(q.w, c.w), __fmul_rn(2.0f, dot));
      unsigned bits = __float_as_uint(d2);
      unsigned fk = bits ^ (0x80000000u | (unsigned)((int)bits >> 31));
      ull key = ((ull)fk << 32) | (unsigned)((t << 10) + ml);
      bool pred = key < thresh;
      ull mask = __ballot(pred);
      if (mask) {                               // uniform branch
        int pos = cnt + __popcll(mask & ltmask);
        if (pred) buf[w][pos] = key;
        cnt += __popcll(mask);
        if (cnt >= 64) {                        // uniform flush
          ull v = buf[w][lane];
          v = bitonic_sort64(v, lane);
          ull vr = __shfl(v, 63 - lane);        // reverse -> desc
          R = minu64(R, vr);                    // bottom-64 of union, bitonic
          R = bitonic_merge64(R, lane);
          thresh = __shfl(R, 15);
          cnt -= 64;
          if (lane < cnt) {                     // shift remainder to front
            ull tmp = buf[w][64 + lane];
            buf[w][lane] = tmp;
          }
        }
      }
    }
  }
  {                                             // final flush (cnt <= 63)
    ull v = (lane < cnt) ? buf[w][lane] : ~0ull;
    v = bitonic_sort64(v, lane);
    ull vr = __shfl(v, 63 - lane);
    R = minu64(R, vr);
    R = bitonic_merge64(R, lane);
  }
  if (lane < KNN_K)
    knnOut[(b * NPT + n) * KNN_K + lane] = (int)(unsigned)(R & 0xFFFFFFFFull);
}

// MLP: unchanged from round 1 (isolate knn change; counters next round).
__global__ __launch_bounds__(128) void mlp_kernel(
    const float* __restrict__ xyz, const float* __restrict__ points,
    const float* __restrict__ wbuf, const int* __restrict__ knn,
    float* __restrict__ out) {
  __shared__ __align__(16) float feat[128 * 68];  // 34816 B
  int tid = threadIdx.x;
  int k = tid & 15, qi = tid >> 4;
  int b = blockIdx.x >> 9;                        // 512 blocks/batch
  int n = ((blockIdx.x & 511) << 3) + qi;
  int center = b * NPT + n;
  int nIdx = knn[center * KNN_K + k];
  int src = b * NPT + nIdx;

  float* row = feat + tid * 68;
  const float4* prow = (const float4*)(points + (size_t)src * 64);
#pragma unroll
  for (int j = 0; j < 16; ++j) ((float4*)row)[j] = prow[j];
  row[64] = xyz[src * 3 + 0] - xyz[center * 3 + 0];
  row[65] = xyz[src * 3 + 1] - xyz[center * 3 + 1];
  row[66] = xyz[src * 3 + 2] - xyz[center * 3 + 2];

  const float* w0t = wbuf + W0T_OFF;
  const float* b0f = wbuf + B0_OFF;
  const float* w1t = wbuf + W1T_OFF;
  const float* b1f = wbuf + B1_OFF;
  const float* w2g = wbuf + W2G_OFF;
  const float* b2f = wbuf + B2_OFF;

  float acc[64];
#pragma unroll
  for (int oc = 0; oc < 64; ++oc) acc[oc] = b0f[oc];
#pragma unroll 1
  for (int ic = 0; ic < 67; ++ic) {
    float x = row[ic];
    const float* w = w0t + ic * 64;
#pragma unroll
    for (int oc = 0; oc < 64; ++oc) acc[oc] = fmaf(w[oc], x, acc[oc]);
  }
#pragma unroll
  for (int oc = 0; oc < 64; ++oc) row[oc] = fmaxf(acc[oc], 0.0f);

#pragma unroll
  for (int oc = 0; oc < 64; ++oc) acc[oc] = b1f[oc];
#pragma unroll 1
  for (int ic = 0; ic < 64; ++ic) {
    float x = row[ic];
    const float* w = w1t + ic * 64;
#pragma unroll
    for (int oc = 0; oc < 64; ++oc) acc[oc] = fmaf(w[oc], x, acc[oc]);
  }
  float h1[64];
#pragma unroll
  for (int oc = 0; oc < 64; ++oc) h1[oc] = fmaxf(acc[oc], 0.0f);

  float4* outRow = (float4*)(out + (size_t)center * 128);
#pragma unroll 1
  for (int g = 0; g < 32; ++g) {
    const float* w = w2g + g * 256;
    float a0 = b2f[g * 4 + 0], a1 = b2f[g * 4 + 1];
    float a2 = b2f[g * 4 + 2], a3 = b2f[g * 4 + 3];
#pragma unroll
    for (int ic = 0; ic < 64; ++ic) {
      float x = h1[ic];
      a0 = fmaf(w[ic * 4 + 0], x, a0);
      a1 = fmaf(w[ic * 4 + 1], x, a1);
      a2 = fmaf(w[ic * 4 + 2], x, a2);
      a3 = fmaf(w[ic * 4 + 3], x, a3);
    }
    a0 = fmaxf(a0, 0.0f); a1 = fmaxf(a1, 0.0f);
    a2 = fmaxf(a2, 0.0f); a3 = fmaxf(a3, 0.0f);
#pragma unroll
    for (int off = 8; off; off >>= 1) {
      a0 = fmaxf(a0, __shfl_xor(a0, off));
      a1 = fmaxf(a1, __shfl_xor(a1, off));
      a2 = fmaxf(a2, __shfl_xor(a2, off));
      a3 = fmaxf(a3, __shfl_xor(a3, off));
    }
    if (k == 0) outRow[g] = make_float4(a0, a1, a2, a3);
  }
}

extern "C" void kernel_launch(void* const* d_in, const int* in_sizes, int n_in,
                              void* d_out, int out_size, void* d_ws, size_t ws_size,
                              hipStream_t stream) {
  const float* xyz    = (const float*)d_in[0];
  const float* points = (const float*)d_in[1];
  float* wsF = (float*)d_ws;
  int* idxBuf = (int*)(wsF + IDX_OFF);
  const float4* cand4 = (const float4*)(wsF + XYZ4_OFF);

  prep_kernel<<<130, 256, 0, stream>>>(
      xyz,
      (const float*)d_in[2],  (const float*)d_in[3],  (const float*)d_in[4],
      (const float*)d_in[5],  (const float*)d_in[6],  (const float*)d_in[7],
      (const float*)d_in[8],  (const float*)d_in[9],  (const float*)d_in[10],
      (const float*)d_in[11], (const float*)d_in[12], (const float*)d_in[13],
      (const float*)d_in[14], (const float*)d_in[15], (const float*)d_in[16],
      (const float*)d_in[17], (const float*)d_in[18], (const float*)d_in[19],
      wsF);
  knn_kernel<<<4096, 256, 0, stream>>>(cand4, idxBuf);
  mlp_kernel<<<2048, 128, 0, stream>>>(xyz, points, wsF, idxBuf, (float*)d_out);
}

// Round 3
// 266.612 us; speedup vs baseline: 3.4054x; 1.6595x over previous
//
#include <hip/hip_runtime.h>

#define NPT   4096
#define KNN_K 16
#define EPSV  1e-5f

// ---- ws float layout ----
#define W0T_OFF 0                  // [67][64] folded (rows 0..63 = points cols, 64..66 = xyz cols)
#define B0_OFF  4288               // [64]
#define W1T_OFF 4352               // [64][64]  (ic-major)
#define B1_OFF  8448               // [64]
#define W2T_OFF 8512               // [64][128] (ic-major)
#define B2_OFF  16704              // [128]
#define IDX_OFF 16832              // int[4*4096*16]
#define XYZ4_OFF 278976            // float4[16384]
#define P_OFF   344512             // float[16384][64]  P = W0p*pts + W0x*xyz + b0
#define Q_OFF   1393088            // float[16384][64]  Q = W0x*xyz

typedef unsigned long long ull;

__global__ void prep_kernel(
    const float* __restrict__ xyz,
    const float* __restrict__ w0, const float* __restrict__ b0, const float* __restrict__ g0,
    const float* __restrict__ be0, const float* __restrict__ rm0, const float* __restrict__ rv0,
    const float* __restrict__ w1, const float* __restrict__ b1, const float* __restrict__ g1,
    const float* __restrict__ be1, const float* __restrict__ rm1, const float* __restrict__ rv1,
    const float* __restrict__ w2, const float* __restrict__ b2, const float* __restrict__ g2,
    const float* __restrict__ be2, const float* __restrict__ rm2, const float* __restrict__ rv2,
    float* __restrict__ ws) {
  int blk = blockIdx.x;
  if (blk < 64) {                        // xyz -> (x,y,z,sq), exact ref arithmetic for knn
    int i = blk * 256 + threadIdx.x;
    const float* p = xyz + i * 3;
    float x = p[0], y = p[1], z = p[2];
    float sq = __fadd_rn(__fadd_rn(__fmul_rn(x, x), __fmul_rn(y, y)), __fmul_rn(z, z));
    ((float4*)(ws + XYZ4_OFF))[i] = make_float4(x, y, z, sq);
    return;
  }
  int i = (blk - 64) * 256 + threadIdx.x;
  if (i < 4288) {                        // w0t: [ic'][oc]
    int oc = i & 63, icp = i >> 6;
    int col = (icp < 64) ? (icp + 3) : (icp - 64);
    float s = g0[oc] * rsqrtf(rv0[oc] + EPSV);
    ws[W0T_OFF + i] = w0[oc * 67 + col] * s;
  } else if (i < 4352) {
    int oc = i - 4288;
    float s = g0[oc] * rsqrtf(rv0[oc] + EPSV);
    ws[i] = (b0[oc] - rm0[oc]) * s + be0[oc];
  } else if (i < 8448) {
    int j = i - 4352; int oc = j & 63, ic = j >> 6;
    float s = g1[oc] * rsqrtf(rv1[oc] + EPSV);
    ws[i] = w1[oc * 64 + ic] * s;
  } else if (i < 8512) {
    int oc = i - 8448;
    float s = g1[oc] * rsqrtf(rv1[oc] + EPSV);
    ws[i] = (b1[oc] - rm1[oc]) * s + be1[oc];
  } else if (i < 16704) {
    int j = i - 8512; int ic = j >> 7, oc = j & 127;
    float s = g2[oc] * rsqrtf(rv2[oc] + EPSV);
    ws[i] = w2[oc * 64 + ic] * s;       // w2t [ic][oc]
  } else if (i < 16832) {
    int oc = i - 16704;
    float s = g2[oc] * rsqrtf(rv2[oc] + EPSV);
    ws[i] = (b2[oc] - rm2[oc]) * s + be2[oc];
  }
}

// P/Q precompute: wave = one point, lane = oc. w0t reads coalesced, points reads
// wave-uniform (scalarized). 70M MAC total.
__global__ __launch_bounds__(256) void pq_kernel(const float* __restrict__ xyz,
                                                 const float* __restrict__ points,
                                                 float* __restrict__ ws) {
  int tid = threadIdx.x;
  int oc = tid & 63;
  int i = blockIdx.x * 4 + (tid >> 6);
  const float* w0t = ws + W0T_OFF;
  float x = xyz[i * 3], y = xyz[i * 3 + 1], z = xyz[i * 3 + 2];
  float qacc = w0t[64 * 64 + oc] * x;
  qacc = fmaf(w0t[65 * 64 + oc], y, qacc);
  qacc = fmaf(w0t[66 * 64 + oc], z, qacc);
  float acc = ws[B0_OFF + oc] + qacc;
  const float* prow = points + (size_t)i * 64;
#pragma unroll 4
  for (int c = 0; c < 64; ++c) acc = fmaf(w0t[c * 64 + oc], prow[c], acc);
  ws[P_OFF + (size_t)i * 64 + oc] = acc;
  ws[Q_OFF + (size_t)i * 64 + oc] = qacc;
}

__device__ __forceinline__ ull minu64(ull a, ull b) { return a < b ? a : b; }
__device__ __forceinline__ ull maxu64(ull a, ull b) { return a > b ? a : b; }

__device__ __forceinline__ ull bitonic_sort64(ull v, int lane) {
#pragma unroll
  for (int k = 2; k <= 64; k <<= 1) {
#pragma unroll
    for (int j = k >> 1; j > 0; j >>= 1) {
      ull o = __shfl_xor(v, j);
      bool lower = (lane & j) == 0;
      bool up = (lane & k) == 0;
      v = (lower == up) ? minu64(v, o) : maxu64(v, o);
    }
  }
  return v;
}

__device__ __forceinline__ ull bitonic_merge64(ull v, int lane) {
#pragma unroll
  for (int j = 32; j > 0; j >>= 1) {
    ull o = __shfl_xor(v, j);
    v = ((lane & j) == 0) ? minu64(v, o) : maxu64(v, o);
  }
  return v;
}

// KNN (unchanged from R2): wave/query threshold-filter + bitonic flush.
__global__ __launch_bounds__(256) void knn_kernel(const float4* __restrict__ cand4,
                                                  int* __restrict__ knnOut) {
  __shared__ __align__(16) float4 tile[1024];
  __shared__ ull buf[4][128];
  int tid = threadIdx.x;
  int lane = tid & 63, w = tid >> 6;
  int b = blockIdx.x >> 10;
  int n = ((blockIdx.x & 1023) << 2) + w;
  const float4* cb = cand4 + b * NPT;

  float4 q = cb[n];
  ull R = ~0ull;
  ull thresh = ~0ull;
  int cnt = 0;
  ull ltmask = (lane == 0) ? 0ull : (~0ull >> (64 - lane));

#pragma unroll 1
  for (int t = 0; t < 4; ++t) {
    __syncthreads();
#pragma unroll
    for (int j = 0; j < 4; ++j) tile[j * 256 + tid] = cb[t * 1024 + j * 256 + tid];
    __syncthreads();
#pragma unroll 1
    for (int i = 0; i < 16; ++i) {
      int ml = (i << 6) + lane;
      float4 c = tile[ml];
      float dot = __fadd_rn(__fadd_rn(__fmul_rn(q.x, c.x), __fmul_rn(q.y, c.y)),
                            __fmul_rn(q.z, c.z));
      float d2 = __fsub_rn(__fadd_rn(q.w, c.w), __fmul_rn(2.0f, dot));
      unsigned bits = __float_as_uint(d2);
      unsigned fk = bits ^ (0x80000000u | (unsigned)((int)bits >> 31));
      ull key = ((ull)fk << 32) | (unsigned)((t << 10) + ml);
      bool pred = key < thresh;
      ull mask = __ballot(pred);
      if (mask) {
        int pos = cnt + __popcll(mask & ltmask);
        if (pred) buf[w][pos] = key;
        cnt += __popcll(mask);
        if (cnt >= 64) {
          ull v = buf[w][lane];
          v = bitonic_sort64(v, lane);
          ull vr = __shfl(v, 63 - lane);
          R = minu64(R, vr);
          R = bitonic_merge64(R, lane);
          thresh = __shfl(R, 15);
          cnt -= 64;
          if (lane < cnt) {
            ull tmp = buf[w][64 + lane];
            buf[w][lane] = tmp;
          }
        }
      }
    }
  }
  {
    ull v = (lane < cnt) ? buf[w][lane] : ~0ull;
    v = bitonic_sort64(v, lane);
    ull vr = __shfl(v, 63 - lane);
    R = minu64(R, vr);
    R = bitonic_merge64(R, lane);
  }
  if (lane < KNN_K)
    knnOut[(b * NPT + n) * KNN_K + lane] = (int)(unsigned)(R & 0xFFFFFFFFull);
}

// MLP v2: register-tiled GEMM. Block = 256 thr = 4 waves; wave = 2 queries x 16 k
// = 32 pairs. h0 = relu(P[src]-Q[q]) -> per-wave LDS A[64ic][32pair]; W1/W2 staged
// in LDS per block. Thread tile 4 pairs x 8 oc: per ic 3 ds_read_b128 + 32 FMA.
// LDS: 4*8K (A) + 16K (W1) + 32K (W2) = 80 KB -> 2 blocks/CU.
__global__ __launch_bounds__(256) void mlp_kernel(
    const float* __restrict__ wbuf, const int* __restrict__ knn,
    float* __restrict__ out) {
  __shared__ __align__(16) float Ash[4][64 * 32];
  __shared__ __align__(16) float W1lds[64 * 64];
  __shared__ __align__(16) float W2lds[64 * 128];
  int tid = threadIdx.x;
  int lane = tid & 63, w = tid >> 6;
  int c = lane & 7, r = lane >> 3;
  int b = blockIdx.x >> 9;                       // 512 blocks/batch, 8 q/block
  int qbase = ((blockIdx.x & 511) << 3) + (w << 1);

  // stage weights (once per block)
  {
    const float4* w1s = (const float4*)(wbuf + W1T_OFF);
    float4* w1d = (float4*)W1lds;
#pragma unroll
    for (int t = 0; t < 4; ++t) w1d[t * 256 + tid] = w1s[t * 256 + tid];
    const float4* w2s = (const float4*)(wbuf + W2T_OFF);
    float4* w2d = (float4*)W2lds;
#pragma unroll
    for (int t = 0; t < 8; ++t) w2d[t * 256 + tid] = w2s[t * 256 + tid];
  }

  // h0 phase: lane covers pair p = lane>>1, channel-half = lane&1
  {
    int p = lane >> 1, half = lane & 1;
    int q = qbase + (p >> 4), k = p & 15;
    int src = knn[(b * NPT + q) * KNN_K + k];
    const float4* Pp = (const float4*)(wbuf + P_OFF + ((size_t)(b * NPT + src) * 64 + half * 32));
    const float4* Qp = (const float4*)(wbuf + Q_OFF + ((size_t)(b * NPT + q) * 64 + half * 32));
    float* Aw = Ash[w];
#pragma unroll
    for (int j = 0; j < 8; ++j) {
      float4 pv = Pp[j];
      float4 qv = Qp[j];
      int ic = half * 32 + j * 4;
      Aw[(ic + 0) * 32 + p] = fmaxf(pv.x - qv.x, 0.0f);
      Aw[(ic + 1) * 32 + p] = fmaxf(pv.y - qv.y, 0.0f);
      Aw[(ic + 2) * 32 + p] = fmaxf(pv.z - qv.z, 0.0f);
      Aw[(ic + 3) * 32 + p] = fmaxf(pv.w - qv.w, 0.0f);
    }
  }
  __syncthreads();   // weights staged + (stronger than needed) A visibility

  float* Aw = Ash[w];
  float acc[4][8];

  // ---- layer 1: h1 = relu(W1 h0) ----
#pragma unroll
  for (int j = 0; j < 8; ++j) {
    float bv = wbuf[B1_OFF + 8 * c + j];
#pragma unroll
    for (int i = 0; i < 4; ++i) acc[i][j] = bv;
  }
#pragma unroll 4
  for (int ic = 0; ic < 64; ++ic) {
    float4 a4 = *(const float4*)(Aw + ic * 32 + 4 * r);
    float4 w40 = *(const float4*)(W1lds + ic * 64 + 8 * c);
    float4 w41 = *(const float4*)(W1lds + ic * 64 + 8 * c + 4);
    float av[4] = {a4.x, a4.y, a4.z, a4.w};
    float wv[8] = {w40.x, w40.y, w40.z, w40.w, w41.x, w41.y, w41.z, w41.w};
#pragma unroll
    for (int i = 0; i < 4; ++i)
#pragma unroll
      for (int j = 0; j < 8; ++j) acc[i][j] = fmaf(av[i], wv[j], acc[i][j]);
  }
  // write h1 back transposed into A (same wave only touches its own A region;
  // in-order per-wave LDS pipe + program order make this safe without barrier)
  __builtin_amdgcn_wave_barrier();
#pragma unroll
  for (int j = 0; j < 8; ++j) {
    int oc = 8 * c + j;
    float4 v = make_float4(fmaxf(acc[0][j], 0.0f), fmaxf(acc[1][j], 0.0f),
                           fmaxf(acc[2][j], 0.0f), fmaxf(acc[3][j], 0.0f));
    *(float4*)(Aw + oc * 32 + 4 * r) = v;
  }
  __builtin_amdgcn_wave_barrier();

  // ---- layer 2 (two 64-oc passes) + relu + max over k + store ----
  int qout = qbase + (lane >> 5);
  bool storer = (lane & 31) < 8;
  float* obase = out + ((size_t)(b * NPT + qout) * 128 + 8 * c);
#pragma unroll 1
  for (int pass = 0; pass < 2; ++pass) {
#pragma unroll
    for (int j = 0; j < 8; ++j) {
      float bv = wbuf[B2_OFF + pass * 64 + 8 * c + j];
#pragma unroll
      for (int i = 0; i < 4; ++i) acc[i][j] = bv;
    }
#pragma unroll 4
    for (int ic = 0; ic < 64; ++ic) {
      float4 a4 = *(const float4*)(Aw + ic * 32 + 4 * r);
      const float* wrow = W2lds + ic * 128 + pass * 64 + 8 * c;
      float4 w40 = *(const float4*)(wrow);
      float4 w41 = *(const float4*)(wrow + 4);
      float av[4] = {a4.x, a4.y, a4.z, a4.w};
      float wv[8] = {w40.x, w40.y, w40.z, w40.w, w41.x, w41.y, w41.z, w41.w};
#pragma unroll
      for (int i = 0; i < 4; ++i)
#pragma unroll
        for (int j = 0; j < 8; ++j) acc[i][j] = fmaf(av[i], wv[j], acc[i][j]);
    }
    float m[8];
#pragma unroll
    for (int j = 0; j < 8; ++j) {
      float v = fmaxf(fmaxf(acc[0][j], acc[1][j]), fmaxf(acc[2][j], acc[3][j]));
      v = fmaxf(v, 0.0f);
      v = fmaxf(v, __shfl_xor(v, 8));
      v = fmaxf(v, __shfl_xor(v, 16));
      m[j] = v;
    }
    if (storer) {
      *(float4*)(obase + pass * 64)     = make_float4(m[0], m[1], m[2], m[3]);
      *(float4*)(obase + pass * 64 + 4) = make_float4(m[4], m[5], m[6], m[7]);
    }
  }
}

extern "C" void kernel_launch(void* const* d_in, const int* in_sizes, int n_in,
                              void* d_out, int out_size, void* d_ws, size_t ws_size,
                              hipStream_t stream) {
  const float* xyz    = (const float*)d_in[0];
  const float* points = (const float*)d_in[1];
  float* wsF = (float*)d_ws;
  int* idxBuf = (int*)(wsF + IDX_OFF);
  const float4* cand4 = (const float4*)(wsF + XYZ4_OFF);

  prep_kernel<<<130, 256, 0, stream>>>(
      xyz,
      (const float*)d_in[2],  (const float*)d_in[3],  (const float*)d_in[4],
      (const float*)d_in[5],  (const float*)d_in[6],  (const float*)d_in[7],
      (const float*)d_in[8],  (const float*)d_in[9],  (const float*)d_in[10],
      (const float*)d_in[11], (const float*)d_in[12], (const float*)d_in[13],
      (const float*)d_in[14], (const float*)d_in[15], (const float*)d_in[16],
      (const float*)d_in[17], (const float*)d_in[18], (const float*)d_in[19],
      wsF);
  pq_kernel<<<4096, 256, 0, stream>>>(xyz, points, wsF);
  knn_kernel<<<4096, 256, 0, stream>>>(cand4, idxBuf);
  mlp_kernel<<<2048, 256, 0, stream>>>(wsF, idxBuf, (float*)d_out);
}